// Round 13
// baseline (205.806 us; speedup 1.0000x reference)
//
#include <hip/hip_runtime.h>
#include <hip/hip_bf16.h>

typedef short short8 __attribute__((ext_vector_type(8)));
typedef float f32x4 __attribute__((ext_vector_type(4)));
typedef unsigned short ushort_t;

#define AS1 __attribute__((address_space(1)))
#define AS3 __attribute__((address_space(3)))

__device__ __forceinline__ ushort_t f2bf(float f) {
    unsigned u = __builtin_bit_cast(unsigned, f);
    unsigned r = (u + 0x7FFFu + ((u >> 16) & 1u)) >> 16;
    return (ushort_t)r;
}

__device__ __forceinline__ void gload_lds16(const void* g, void* l) {
    __builtin_amdgcn_global_load_lds((const AS1 unsigned*)g, (AS3 unsigned*)l, 16, 0, 0);
}

// -------------------------------------------------------------------------
// K1: per (n, row h): stage x[n][:, h, :] as bf16 [256px][64c] in LDS
// (XOR-swizzled), (a) write padded-NHWC bf16 x_t (+ zero col borders; the
// h==0 / h==255 blocks also zero the padded top/bottom border rows),
// (b) attention dot via MFMA -> ATOMIC-FREE partials:
// s_part[n][h][d] = sum_px relu(w1[d,:]·x[:,px]+b1[d])  (no memset needed)
// -------------------------------------------------------------------------
__global__ __launch_bounds__(256) void dc_k1_stage_attn(
    const float* __restrict__ x, const float* __restrict__ w1,
    const float* __restrict__ b1, float* __restrict__ s_part,
    ushort_t* __restrict__ x_t)
{
    __shared__ unsigned xt32[256 * 32];   // 256 px * 64c bf16, swizzled
    __shared__ ushort_t w1s[16 * 64];
    __shared__ float sacc[16];

    const int n = blockIdx.y, h = blockIdx.x, t = threadIdx.x;

    // zero padded border rows (absorbed K0)
    if (h == 0 || h == 255) {
        const int row = (h == 0) ? 0 : 257;
        short8 z = {0, 0, 0, 0, 0, 0, 0, 0};
        short8* p = reinterpret_cast<short8*>(x_t + (size_t)(n * 258 + row) * 258 * 64);
        for (int i = t; i < 2064; i += 256) p[i] = z;  // 258*64/8
    }

    if (t < 16) sacc[t] = 0.f;
#pragma unroll
    for (int q = 0; q < 4; ++q) { int idx = q * 256 + t; w1s[idx] = f2bf(w1[idx]); }

    const float* xr = x + ((size_t)n * 64) * 65536 + (size_t)h * 256;
    const int sw = (t & 7) << 2;
    for (int cp = 0; cp < 32; ++cp) {
        float a = xr[(size_t)(2 * cp) * 65536 + t];
        float b = xr[(size_t)(2 * cp + 1) * 65536 + t];
        xt32[(t * 32 + cp) ^ sw] = (unsigned)f2bf(a) | ((unsigned)f2bf(b) << 16);
    }
    __syncthreads();

    const int lane = t & 63, wv = t >> 6, l15 = lane & 15, lg = lane >> 4;
    const short8* xt8 = reinterpret_cast<const short8*>(xt32);
    const short8* w18 = reinterpret_cast<const short8*>(w1s);

    short8 a0 = w18[l15 * 8 + lg];
    short8 a1 = w18[l15 * 8 + 4 + lg];
    float b1v[4];
#pragma unroll
    for (int r = 0; r < 4; ++r) b1v[r] = b1[lg * 4 + r];

    float rs[4] = {0.f, 0.f, 0.f, 0.f};
#pragma unroll
    for (int q = 0; q < 4; ++q) {
        int px = (wv * 4 + q) * 16 + l15;
        int pb = px * 8, ps = px & 7;
        short8 bb0 = xt8[pb + (lg ^ ps)];
        short8 bb1 = xt8[pb + ((4 + lg) ^ ps)];
        f32x4 hacc = {0.f, 0.f, 0.f, 0.f};
        hacc = __builtin_amdgcn_mfma_f32_16x16x32_bf16(a0, bb0, hacc, 0, 0, 0);
        hacc = __builtin_amdgcn_mfma_f32_16x16x32_bf16(a1, bb1, hacc, 0, 0, 0);
#pragma unroll
        for (int r = 0; r < 4; ++r) rs[r] += fmaxf(hacc[r] + b1v[r], 0.f);
    }
#pragma unroll
    for (int off = 1; off < 16; off <<= 1)
#pragma unroll
        for (int r = 0; r < 4; ++r) rs[r] += __shfl_xor(rs[r], off);
    if (l15 == 0) {
#pragma unroll
        for (int r = 0; r < 4; ++r) atomicAdd(&sacc[lg * 4 + r], rs[r]);
    }
    __syncthreads();
    // atomic-free partial write (every slot written unconditionally)
    if (t < 16) s_part[((size_t)n * 256 + h) * 16 + t] = sacc[t];

    // write-out padded NHWC bf16 (interior cols 1..256 of padded row h+1)
    ushort_t* xo = x_t + (((size_t)n * 258 + h + 1) * 258 + 1) * 64;
    const int cb = t & 7, pxr = t >> 3;
#pragma unroll
    for (int rr = 0; rr < 8; ++rr) {
        int px = rr * 32 + pxr;
        short8 v = xt8[px * 8 + (cb ^ (px & 7))];
        *reinterpret_cast<short8*>(xo + (size_t)px * 64 + cb * 8) = v;
    }
    // zero the left/right padded columns of this row
    if (t < 16) {
        short8 z = {0, 0, 0, 0, 0, 0, 0, 0};
        size_t colbase = (((size_t)n * 258 + h + 1) * 258 + ((t < 8) ? 0 : 257)) * 64;
        reinterpret_cast<short8*>(x_t + colbase)[t & 7] = z;
    }
}

// -------------------------------------------------------------------------
// K2 (merged): per block (o,n): reduce s_part -> s[n][:], recompute pi[n],
// aggregate weights -> fragment-major A_frag[n][ks][mf][lane][8]
// (ks=(ki*3+kj)*2+cc), and b_agg[n][o].
// -------------------------------------------------------------------------
__global__ void dc_k2_agg(const float* __restrict__ s_part,
                          const float* __restrict__ w2,
                          const float* __restrict__ b2,
                          const float* __restrict__ b_bank,
                          const float* __restrict__ w_bank,
                          float* __restrict__ b_agg,
                          ushort_t* __restrict__ A_frag)
{
    __shared__ float lw[2304];  // one o-row: [4 kw][64 c][9 ij]
    __shared__ float sS[16];
    const int o = blockIdx.x, n = blockIdx.y, t = threadIdx.x;  // 64 threads

    // issue the w_bank load first (latency overlap with the reduction)
    const float* wrow = w_bank + (size_t)o * 2304;
    for (int rr = 0; rr < 36; ++rr) lw[rr * 64 + t] = wrow[rr * 64 + t];

    // reduce s_part over h: lane t handles d=t&15, h-stride 4 group t>>4
    const float* sp = s_part + (size_t)n * 4096;
    float part = 0.f;
    for (int h = (t >> 4); h < 256; h += 4) part += sp[h * 16 + (t & 15)];
    part += __shfl_xor(part, 16);
    part += __shfl_xor(part, 32);
    if (t < 16) sS[t] = part;
    __syncthreads();

    float z[4];
#pragma unroll
    for (int e = 0; e < 4; ++e) {
        float p = 0.f;
        for (int d = 0; d < 16; ++d) p += w2[e * 16 + d] * sS[d];
        z[e] = (b2[e] + p * (1.f / 65536.f)) * (1.f / 30.f);
    }
    float m = fmaxf(fmaxf(z[0], z[1]), fmaxf(z[2], z[3]));
    float ex[4], sum = 0.f;
#pragma unroll
    for (int e = 0; e < 4; ++e) { ex[e] = expf(z[e] - m); sum += ex[e]; }
    float inv = 1.f / sum;
    const float p0 = ex[0] * inv, p1 = ex[1] * inv, p2 = ex[2] * inv, p3 = ex[3] * inv;

    const int c = t;
    const int cc = c >> 5, lg = (c >> 3) & 3, e = c & 7;
    const int mf = o >> 4, l15 = o & 15;
    ushort_t* base = A_frag + (size_t)n * 18 * 4 * 64 * 8;
#pragma unroll
    for (int ij = 0; ij < 9; ++ij) {
        float v = p0 * lw[0 * 576 + c * 9 + ij] + p1 * lw[1 * 576 + c * 9 + ij]
                + p2 * lw[2 * 576 + c * 9 + ij] + p3 * lw[3 * 576 + c * 9 + ij];
        int ks = ij * 2 + cc;
        base[(((ks * 4 + mf) * 64) + (lg * 16 + l15)) * 8 + e] = f2bf(v);
    }
    if (t == 0)
        b_agg[n * 64 + o] = p0 * b_bank[o * 4 + 0] + p1 * b_bank[o * 4 + 1]
                          + p2 * b_bank[o * 4 + 2] + p3 * b_bank[o * 4 + 3];
}

// -------------------------------------------------------------------------
// K3: persistent row-strip implicit-GEMM conv (R12, unchanged, best).
// 2 output rows/iter, 8 waves (512 thr) = 2 waves/SIMD; wave = 64 Co x
// 16 px x 2 rows. Per ki-phase all 12 B ds_reads batched at phase start;
// A 1-step double buffer. LDS: A (72 KB) + 5-slot ring (5 x 17408 B).
// Stage r4 at iter start, r5 after ki=0. Stores last, vmcnt(31).
// -------------------------------------------------------------------------
__global__ __launch_bounds__(512, 1) void dc_k3_conv(
    const ushort_t* __restrict__ x_t, const ushort_t* __restrict__ A_frag,
    const float* __restrict__ b_agg, float* __restrict__ out)
{
    __shared__ char lds[73728 + 5 * 17408];   // 160,768 B (<= 160 KiB)
    char* ldsA = lds;
    char* ldsW = lds + 73728;

    int bid = blockIdx.x;
    int nb = (bid & 7) * 32 + (bid >> 3);   // XCD-chunked swizzle (256%8==0)
    const int n = nb >> 4;
    const int half = nb & 1;
    const int strip = (nb >> 1) & 7;
    const int h0 = strip * 32;
    const int w0 = half << 7;

    const int t = threadIdx.x, lane = t & 63, wv = t >> 6;   // wv in 0..7
    const int l15 = lane & 15, lg = lane >> 4;
    const int pxl = wv * 16;                                  // 16-px slice

    const char* srcb = (const char*)x_t;
    const char* Asrc = (const char*)A_frag + (size_t)n * 73728;

    auto stage_row = [&](int rr, int slot) {
        size_t rowoff = ((size_t)(n * 258 + h0 + rr) * 258 + w0) * 128;
        char* dst = ldsW + slot * 17408;
        for (int k = wv; k < 17; k += 8) {
            unsigned q = k * 1024 + lane * 16;
            unsigned so = q ^ (((q >> 7) & 7) << 4);
            gload_lds16(srcb + rowoff + so, dst + k * 1024);
        }
    };

    // ---- prologue: stage A (72 KB, 9 chunks/wave) + rows 0..3 ----
    for (int q = 0; q < 9; ++q) {
        int j = wv * 9 + q;
        gload_lds16(Asrc + j * 1024 + lane * 16, ldsA + j * 1024);
    }
    for (int r = 0; r < 4; ++r) stage_row(r, r);
    asm volatile("s_waitcnt vmcnt(0)" ::: "memory");
    __builtin_amdgcn_s_barrier();
    __builtin_amdgcn_sched_barrier(0);

    int boff[3][2];
#pragma unroll
    for (int kj = 0; kj < 3; ++kj)
#pragma unroll
        for (int cc = 0; cc < 2; ++cc) {
            int colL = pxl + l15 + kj;
            boff[kj][cc] = (colL * 128 + cc * 64 + lg * 16)
                           ^ ((colL & 7) << 4);
        }
    const int aoff = lane * 16;

    const float* bn = b_agg + n * 64;
    float bv[4][4];
#pragma unroll
    for (int mf = 0; mf < 4; ++mf)
#pragma unroll
        for (int r = 0; r < 4; ++r) bv[mf][r] = bn[mf * 16 + lg * 4 + r];

#pragma unroll 1
    for (int j = 0; j < 16; ++j) {
        const int r0 = 2 * j;
        const int r4 = r0 + 4, r5 = r0 + 5;

        if (r4 <= 33) stage_row(r4, r4 % 5);
        __builtin_amdgcn_sched_barrier(0);

        const char* sb[4] = { ldsW + (r0 % 5) * 17408,
                              ldsW + ((r0 + 1) % 5) * 17408,
                              ldsW + ((r0 + 2) % 5) * 17408,
                              ldsW + ((r0 + 3) % 5) * 17408 };

        f32x4 acc[4][2] = {};             // [mf][o]

#pragma unroll
        for (int ki = 0; ki < 3; ++ki) {
            short8 bph[6][2];             // [s][o], static indices
#pragma unroll
            for (int s = 0; s < 6; ++s)
#pragma unroll
                for (int o = 0; o < 2; ++o)
                    bph[s][o] = *reinterpret_cast<const short8*>(
                        sb[ki + o] + boff[s >> 1][s & 1]);

            short8 afb[2][4];
#pragma unroll
            for (int mf = 0; mf < 4; ++mf)
                afb[0][mf] = *reinterpret_cast<const short8*>(
                    ldsA + (ki * 6) * 4096 + mf * 1024 + aoff);

#pragma unroll
            for (int s = 0; s < 6; ++s) {
                const int cur = s & 1, nxt = cur ^ 1;
                if (s < 5) {
#pragma unroll
                    for (int mf = 0; mf < 4; ++mf)
                        afb[nxt][mf] = *reinterpret_cast<const short8*>(
                            ldsA + (ki * 6 + s + 1) * 4096 + mf * 1024 + aoff);
                }
                __builtin_amdgcn_s_setprio(1);
#pragma unroll
                for (int mf = 0; mf < 4; ++mf)
#pragma unroll
                    for (int o = 0; o < 2; ++o)
                        acc[mf][o] = __builtin_amdgcn_mfma_f32_16x16x32_bf16(
                            afb[cur][mf], bph[s][o], acc[mf][o], 0, 0, 0);
                __builtin_amdgcn_s_setprio(0);
            }

            if (ki == 0) {
                __builtin_amdgcn_s_barrier();
                if (r5 <= 33) stage_row(r5, r0 % 5);
                __builtin_amdgcn_sched_barrier(0);
            }
        }

#pragma unroll
        for (int o = 0; o < 2; ++o) {
            const int h = h0 + r0 + o;
#pragma unroll
            for (int mf = 0; mf < 4; ++mf) {
                const int col = w0 + pxl + l15;
#pragma unroll
                for (int r = 0; r < 4; ++r)
                    out[((size_t)(n * 64 + mf * 16 + lg * 4 + r) << 16)
                        + (size_t)h * 256 + col] = acc[mf][o][r] + bv[mf][r];
            }
        }
        __builtin_amdgcn_sched_barrier(0);
        asm volatile("s_waitcnt vmcnt(31)" ::: "memory");
        __builtin_amdgcn_s_barrier();
        __builtin_amdgcn_sched_barrier(0);
    }
}

// -------------------------------------------------------------------------
extern "C" void kernel_launch(void* const* d_in, const int* in_sizes, int n_in,
                              void* d_out, int out_size, void* d_ws, size_t ws_size,
                              hipStream_t stream) {
    const float* x      = (const float*)d_in[0];
    const float* w_bank = (const float*)d_in[1];
    const float* b_bank = (const float*)d_in[2];
    const float* att_w1 = (const float*)d_in[3];
    const float* att_b1 = (const float*)d_in[4];
    const float* att_w2 = (const float*)d_in[5];
    const float* att_b2 = (const float*)d_in[6];
    float* out = (float*)d_out;

    char* ws = (char*)d_ws;
    float*    s_part = (float*)ws;                     // 256 KB [16][256][16]
    float*    b_agg  = (float*)(ws + 262144);          // 4 KB
    ushort_t* A_frag = (ushort_t*)(ws + 270336);       // 1.125 MB
    ushort_t* x_t    = (ushort_t*)(ws + (2ull << 20)); // padded NHWC bf16, ~136.3 MB

    dc_k1_stage_attn<<<dim3(256, 16), 256, 0, stream>>>(x, att_w1, att_b1, s_part, x_t);
    dc_k2_agg<<<dim3(64, 16), 64, 0, stream>>>(s_part, att_w2, att_b2, b_bank,
                                               w_bank, b_agg, A_frag);
    dc_k3_conv<<<256, 512, 0, stream>>>(x_t, A_frag, b_agg, out);
}

// Round 14
// 189.367 us; speedup vs baseline: 1.0868x; 1.0868x over previous
//
#include <hip/hip_runtime.h>
#include <hip/hip_bf16.h>

typedef short short8 __attribute__((ext_vector_type(8)));
typedef float f32x4 __attribute__((ext_vector_type(4)));
typedef unsigned short ushort_t;

#define AS1 __attribute__((address_space(1)))
#define AS3 __attribute__((address_space(3)))

__device__ __forceinline__ ushort_t f2bf(float f) {
    unsigned u = __builtin_bit_cast(unsigned, f);
    unsigned r = (u + 0x7FFFu + ((u >> 16) & 1u)) >> 16;
    return (ushort_t)r;
}

__device__ __forceinline__ void gload_lds16(const void* g, void* l) {
    __builtin_amdgcn_global_load_lds((const AS1 unsigned*)g, (AS3 unsigned*)l, 16, 0, 0);
}

// -------------------------------------------------------------------------
// K1: per (n, row h): stage x[n][:, h, :] as bf16 [256px][64c] in LDS
// (XOR-swizzled), (a) write padded-NHWC bf16 x_t (+ zero col borders; the
// h==0 / h==255 blocks also zero the padded top/bottom border rows),
// (b) attention dot via MFMA: s[n][d] += sum_px relu(w1[d,:]·x[:,px]+b1[d])
// -------------------------------------------------------------------------
__global__ __launch_bounds__(256) void dc_k1_stage_attn(
    const float* __restrict__ x, const float* __restrict__ w1,
    const float* __restrict__ b1, float* __restrict__ s_glob,
    ushort_t* __restrict__ x_t)
{
    __shared__ unsigned xt32[256 * 32];   // 256 px * 64c bf16, swizzled
    __shared__ ushort_t w1s[16 * 64];
    __shared__ float sacc[16];

    const int n = blockIdx.y, h = blockIdx.x, t = threadIdx.x;

    // absorbed K0: zero padded border rows
    if (h == 0 || h == 255) {
        const int row = (h == 0) ? 0 : 257;
        short8 z = {0, 0, 0, 0, 0, 0, 0, 0};
        short8* p = reinterpret_cast<short8*>(x_t + (size_t)(n * 258 + row) * 258 * 64);
        for (int i = t; i < 2064; i += 256) p[i] = z;  // 258*64/8
    }

    if (t < 16) sacc[t] = 0.f;
#pragma unroll
    for (int q = 0; q < 4; ++q) { int idx = q * 256 + t; w1s[idx] = f2bf(w1[idx]); }

    const float* xr = x + ((size_t)n * 64) * 65536 + (size_t)h * 256;
    const int sw = (t & 7) << 2;
    for (int cp = 0; cp < 32; ++cp) {
        float a = xr[(size_t)(2 * cp) * 65536 + t];
        float b = xr[(size_t)(2 * cp + 1) * 65536 + t];
        xt32[(t * 32 + cp) ^ sw] = (unsigned)f2bf(a) | ((unsigned)f2bf(b) << 16);
    }
    __syncthreads();

    const int lane = t & 63, wv = t >> 6, l15 = lane & 15, lg = lane >> 4;
    const short8* xt8 = reinterpret_cast<const short8*>(xt32);
    const short8* w18 = reinterpret_cast<const short8*>(w1s);

    short8 a0 = w18[l15 * 8 + lg];
    short8 a1 = w18[l15 * 8 + 4 + lg];
    float b1v[4];
#pragma unroll
    for (int r = 0; r < 4; ++r) b1v[r] = b1[lg * 4 + r];

    float rs[4] = {0.f, 0.f, 0.f, 0.f};
#pragma unroll
    for (int q = 0; q < 4; ++q) {
        int px = (wv * 4 + q) * 16 + l15;
        int pb = px * 8, ps = px & 7;
        short8 bb0 = xt8[pb + (lg ^ ps)];
        short8 bb1 = xt8[pb + ((4 + lg) ^ ps)];
        f32x4 hacc = {0.f, 0.f, 0.f, 0.f};
        hacc = __builtin_amdgcn_mfma_f32_16x16x32_bf16(a0, bb0, hacc, 0, 0, 0);
        hacc = __builtin_amdgcn_mfma_f32_16x16x32_bf16(a1, bb1, hacc, 0, 0, 0);
#pragma unroll
        for (int r = 0; r < 4; ++r) rs[r] += fmaxf(hacc[r] + b1v[r], 0.f);
    }
#pragma unroll
    for (int off = 1; off < 16; off <<= 1)
#pragma unroll
        for (int r = 0; r < 4; ++r) rs[r] += __shfl_xor(rs[r], off);
    if (l15 == 0) {
#pragma unroll
        for (int r = 0; r < 4; ++r) atomicAdd(&sacc[lg * 4 + r], rs[r]);
    }
    __syncthreads();
    if (t < 16) atomicAdd(&s_glob[n * 16 + t], sacc[t]);

    // write-out padded NHWC bf16 (interior cols 1..256 of padded row h+1)
    ushort_t* xo = x_t + (((size_t)n * 258 + h + 1) * 258 + 1) * 64;
    const int cb = t & 7, pxr = t >> 3;
#pragma unroll
    for (int rr = 0; rr < 8; ++rr) {
        int px = rr * 32 + pxr;
        short8 v = xt8[px * 8 + (cb ^ (px & 7))];
        *reinterpret_cast<short8*>(xo + (size_t)px * 64 + cb * 8) = v;
    }
    // zero the left/right padded columns of this row
    if (t < 16) {
        short8 z = {0, 0, 0, 0, 0, 0, 0, 0};
        size_t colbase = (((size_t)n * 258 + h + 1) * 258 + ((t < 8) ? 0 : 257)) * 64;
        reinterpret_cast<short8*>(x_t + colbase)[t & 7] = z;
    }
}

// -------------------------------------------------------------------------
// K2 (merged): per block (o,n): recompute pi[n] from s_glob, aggregate
// weights -> fragment-major A_frag[n][ks][mf][lane][8] (ks=(ki*3+kj)*2+cc),
// and b_agg[n][o].
// -------------------------------------------------------------------------
__global__ void dc_k2_agg(const float* __restrict__ s_glob,
                          const float* __restrict__ w2,
                          const float* __restrict__ b2,
                          const float* __restrict__ b_bank,
                          const float* __restrict__ w_bank,
                          float* __restrict__ b_agg,
                          ushort_t* __restrict__ A_frag)
{
    __shared__ float lw[2304];  // one o-row: [4 kw][64 c][9 ij]
    const int o = blockIdx.x, n = blockIdx.y, t = threadIdx.x;  // 64 threads

    float z[4];
#pragma unroll
    for (int e = 0; e < 4; ++e) {
        float p = 0.f;
        for (int d = 0; d < 16; ++d) p += w2[e * 16 + d] * s_glob[n * 16 + d];
        z[e] = (b2[e] + p * (1.f / 65536.f)) * (1.f / 30.f);
    }
    float m = fmaxf(fmaxf(z[0], z[1]), fmaxf(z[2], z[3]));
    float ex[4], sum = 0.f;
#pragma unroll
    for (int e = 0; e < 4; ++e) { ex[e] = expf(z[e] - m); sum += ex[e]; }
    float inv = 1.f / sum;
    const float p0 = ex[0] * inv, p1 = ex[1] * inv, p2 = ex[2] * inv, p3 = ex[3] * inv;

    const float* wrow = w_bank + (size_t)o * 2304;
    for (int rr = 0; rr < 36; ++rr) lw[rr * 64 + t] = wrow[rr * 64 + t];
    __syncthreads();

    const int c = t;
    const int cc = c >> 5, lg = (c >> 3) & 3, e = c & 7;
    const int mf = o >> 4, l15 = o & 15;
    ushort_t* base = A_frag + (size_t)n * 18 * 4 * 64 * 8;
#pragma unroll
    for (int ij = 0; ij < 9; ++ij) {
        float v = p0 * lw[0 * 576 + c * 9 + ij] + p1 * lw[1 * 576 + c * 9 + ij]
                + p2 * lw[2 * 576 + c * 9 + ij] + p3 * lw[3 * 576 + c * 9 + ij];
        int ks = ij * 2 + cc;
        base[(((ks * 4 + mf) * 64) + (lg * 16 + l15)) * 8 + e] = f2bf(v);
    }
    if (t == 0)
        b_agg[n * 64 + o] = p0 * b_bank[o * 4 + 0] + p1 * b_bank[o * 4 + 1]
                          + p2 * b_bank[o * 4 + 2] + p3 * b_bank[o * 4 + 3];
}

// -------------------------------------------------------------------------
// K3: persistent row-strip implicit-GEMM conv (best config, R12).
// 2 output rows/iter, 8 waves (512 thr) = 2 waves/SIMD; wave = 64 Co x
// 16 px x 2 rows. Per ki-phase all 12 B ds_reads batched at phase start;
// A 1-step double buffer. LDS: A (72 KB) + 5-slot ring (5 x 17408 B).
// Stage r4 at iter start, r5 after ki=0. Stores last, vmcnt(31).
// -------------------------------------------------------------------------
__global__ __launch_bounds__(512, 1) void dc_k3_conv(
    const ushort_t* __restrict__ x_t, const ushort_t* __restrict__ A_frag,
    const float* __restrict__ b_agg, float* __restrict__ out)
{
    __shared__ char lds[73728 + 5 * 17408];   // 160,768 B (<= 160 KiB)
    char* ldsA = lds;
    char* ldsW = lds + 73728;

    int bid = blockIdx.x;
    int nb = (bid & 7) * 32 + (bid >> 3);   // XCD-chunked swizzle (256%8==0)
    const int n = nb >> 4;
    const int half = nb & 1;
    const int strip = (nb >> 1) & 7;
    const int h0 = strip * 32;
    const int w0 = half << 7;

    const int t = threadIdx.x, lane = t & 63, wv = t >> 6;   // wv in 0..7
    const int l15 = lane & 15, lg = lane >> 4;
    const int pxl = wv * 16;                                  // 16-px slice

    const char* srcb = (const char*)x_t;
    const char* Asrc = (const char*)A_frag + (size_t)n * 73728;

    auto stage_row = [&](int rr, int slot) {
        size_t rowoff = ((size_t)(n * 258 + h0 + rr) * 258 + w0) * 128;
        char* dst = ldsW + slot * 17408;
        for (int k = wv; k < 17; k += 8) {
            unsigned q = k * 1024 + lane * 16;
            unsigned so = q ^ (((q >> 7) & 7) << 4);
            gload_lds16(srcb + rowoff + so, dst + k * 1024);
        }
    };

    // ---- prologue: stage A (72 KB, 9 chunks/wave) + rows 0..3 ----
    for (int q = 0; q < 9; ++q) {
        int j = wv * 9 + q;
        gload_lds16(Asrc + j * 1024 + lane * 16, ldsA + j * 1024);
    }
    for (int r = 0; r < 4; ++r) stage_row(r, r);
    asm volatile("s_waitcnt vmcnt(0)" ::: "memory");
    __builtin_amdgcn_s_barrier();
    __builtin_amdgcn_sched_barrier(0);

    int boff[3][2];
#pragma unroll
    for (int kj = 0; kj < 3; ++kj)
#pragma unroll
        for (int cc = 0; cc < 2; ++cc) {
            int colL = pxl + l15 + kj;
            boff[kj][cc] = (colL * 128 + cc * 64 + lg * 16)
                           ^ ((colL & 7) << 4);
        }
    const int aoff = lane * 16;

    const float* bn = b_agg + n * 64;
    float bv[4][4];
#pragma unroll
    for (int mf = 0; mf < 4; ++mf)
#pragma unroll
        for (int r = 0; r < 4; ++r) bv[mf][r] = bn[mf * 16 + lg * 4 + r];

#pragma unroll 1
    for (int j = 0; j < 16; ++j) {
        const int r0 = 2 * j;
        const int r4 = r0 + 4, r5 = r0 + 5;

        if (r4 <= 33) stage_row(r4, r4 % 5);
        __builtin_amdgcn_sched_barrier(0);

        const char* sb[4] = { ldsW + (r0 % 5) * 17408,
                              ldsW + ((r0 + 1) % 5) * 17408,
                              ldsW + ((r0 + 2) % 5) * 17408,
                              ldsW + ((r0 + 3) % 5) * 17408 };

        f32x4 acc[4][2] = {};             // [mf][o]

#pragma unroll
        for (int ki = 0; ki < 3; ++ki) {
            short8 bph[6][2];             // [s][o], static indices
#pragma unroll
            for (int s = 0; s < 6; ++s)
#pragma unroll
                for (int o = 0; o < 2; ++o)
                    bph[s][o] = *reinterpret_cast<const short8*>(
                        sb[ki + o] + boff[s >> 1][s & 1]);

            short8 afb[2][4];
#pragma unroll
            for (int mf = 0; mf < 4; ++mf)
                afb[0][mf] = *reinterpret_cast<const short8*>(
                    ldsA + (ki * 6) * 4096 + mf * 1024 + aoff);

#pragma unroll
            for (int s = 0; s < 6; ++s) {
                const int cur = s & 1, nxt = cur ^ 1;
                if (s < 5) {
#pragma unroll
                    for (int mf = 0; mf < 4; ++mf)
                        afb[nxt][mf] = *reinterpret_cast<const short8*>(
                            ldsA + (ki * 6 + s + 1) * 4096 + mf * 1024 + aoff);
                }
                __builtin_amdgcn_s_setprio(1);
#pragma unroll
                for (int mf = 0; mf < 4; ++mf)
#pragma unroll
                    for (int o = 0; o < 2; ++o)
                        acc[mf][o] = __builtin_amdgcn_mfma_f32_16x16x32_bf16(
                            afb[cur][mf], bph[s][o], acc[mf][o], 0, 0, 0);
                __builtin_amdgcn_s_setprio(0);
            }

            if (ki == 0) {
                __builtin_amdgcn_s_barrier();
                if (r5 <= 33) stage_row(r5, r0 % 5);
                __builtin_amdgcn_sched_barrier(0);
            }
        }

#pragma unroll
        for (int o = 0; o < 2; ++o) {
            const int h = h0 + r0 + o;
#pragma unroll
            for (int mf = 0; mf < 4; ++mf) {
                const int col = w0 + pxl + l15;
#pragma unroll
                for (int r = 0; r < 4; ++r)
                    out[((size_t)(n * 64 + mf * 16 + lg * 4 + r) << 16)
                        + (size_t)h * 256 + col] = acc[mf][o][r] + bv[mf][r];
            }
        }
        __builtin_amdgcn_sched_barrier(0);
        asm volatile("s_waitcnt vmcnt(31)" ::: "memory");
        __builtin_amdgcn_s_barrier();
        __builtin_amdgcn_sched_barrier(0);
    }
}

// -------------------------------------------------------------------------
extern "C" void kernel_launch(void* const* d_in, const int* in_sizes, int n_in,
                              void* d_out, int out_size, void* d_ws, size_t ws_size,
                              hipStream_t stream) {
    const float* x      = (const float*)d_in[0];
    const float* w_bank = (const float*)d_in[1];
    const float* b_bank = (const float*)d_in[2];
    const float* att_w1 = (const float*)d_in[3];
    const float* att_b1 = (const float*)d_in[4];
    const float* att_w2 = (const float*)d_in[5];
    const float* att_b2 = (const float*)d_in[6];
    float* out = (float*)d_out;

    char* ws = (char*)d_ws;
    float*    s_glob = (float*)ws;                     // 1 KB
    float*    b_agg  = (float*)(ws + 2048);            // 4 KB
    ushort_t* A_frag = (ushort_t*)(ws + 8192);         // 1.125 MB
    ushort_t* x_t    = (ushort_t*)(ws + (2ull << 20)); // padded NHWC bf16, ~136.3 MB

    hipMemsetAsync(s_glob, 0, 16 * 16 * sizeof(float), stream);

    dc_k1_stage_attn<<<dim3(256, 16), 256, 0, stream>>>(x, att_w1, att_b1, s_glob, x_t);
    dc_k2_agg<<<dim3(64, 16), 64, 0, stream>>>(s_glob, att_w2, att_b2, b_bank,
                                               w_bank, b_agg, A_frag);
    dc_k3_conv<<<256, 512, 0, stream>>>(x_t, A_frag, b_agg, out);
}